// Round 3
// baseline (39.080 us; speedup 1.0000x reference)
//
#include <hip/hip_runtime.h>
#include <math.h>

// MoE router: x [16384, 2048] f32, gate_w [8, 2048] f32
// outputs (concatenated f32): weights [16384,2] | mask [8,2,16384] | logits [16384,8]

constexpr int kN = 16384;
constexpr int kD = 2048;
constexpr int kE = 8;

using f4 = __attribute__((ext_vector_type(4))) float;

__global__ __launch_bounds__(512, 4)   // 2 blocks/CU (LDS-limited anyway)
void moe_router_kernel(const float* __restrict__ x,
                       const float* __restrict__ gw,
                       float* __restrict__ out)
{
    __shared__ float sg[kE * kD];      // 64 KiB gate stage

    const int tid  = threadIdx.x;
    const int lane = tid & 63;
    const int wv   = tid >> 6;                     // 0..7
    const int n0   = blockIdx.x * 32 + wv * 4;     // 4 rows per wave

    // ---- stage gate_w -> LDS (once per block; coalesced f4, keep in L2) ----
#pragma unroll
    for (int j = 0; j < 8; ++j) {
        const int idx = (j * 512 + tid) * 4;       // covers 16384 floats
        *reinterpret_cast<f4*>(sg + idx) = *reinterpret_cast<const f4*>(gw + idx);
    }
    __syncthreads();

    const float* xr = x + (long)n0 * kD;

    float acc[4][8];
#pragma unroll
    for (int r = 0; r < 4; ++r)
#pragma unroll
        for (int e = 0; e < 8; ++e) acc[r][e] = 0.f;

    // ---- main sweep: x double-buffered in regs; vmcnt queue is pure x ----
    f4 xv[4], xn[4];
#pragma unroll
    for (int r = 0; r < 4; ++r)
        xv[r] = __builtin_nontemporal_load(
            reinterpret_cast<const f4*>(xr + (long)r * kD + lane * 4));

#pragma unroll 1
    for (int it = 0; it < 8; ++it) {
        if (it < 7) {                               // uniform branch, cheap
            const int cn = (it + 1) * 256 + lane * 4;
#pragma unroll
            for (int r = 0; r < 4; ++r)
                xn[r] = __builtin_nontemporal_load(
                    reinterpret_cast<const f4*>(xr + (long)r * kD + cn));
        }
        const int c = it * 256 + lane * 4;
        // two 4-expert batches: halves live g-regs (fits 128-VGPR cap, no spill)
        f4 g[4];
#pragma unroll
        for (int e = 0; e < 4; ++e)
            g[e] = *reinterpret_cast<const f4*>(sg + e * kD + c);
#pragma unroll
        for (int r = 0; r < 4; ++r)
#pragma unroll
            for (int e = 0; e < 4; ++e) {
                acc[r][e] = fmaf(xv[r].x, g[e].x, acc[r][e]);
                acc[r][e] = fmaf(xv[r].y, g[e].y, acc[r][e]);
                acc[r][e] = fmaf(xv[r].z, g[e].z, acc[r][e]);
                acc[r][e] = fmaf(xv[r].w, g[e].w, acc[r][e]);
            }
#pragma unroll
        for (int e = 0; e < 4; ++e)
            g[e] = *reinterpret_cast<const f4*>(sg + (e + 4) * kD + c);
#pragma unroll
        for (int r = 0; r < 4; ++r)
#pragma unroll
            for (int e = 0; e < 4; ++e) {
                acc[r][e + 4] = fmaf(xv[r].x, g[e].x, acc[r][e + 4]);
                acc[r][e + 4] = fmaf(xv[r].y, g[e].y, acc[r][e + 4]);
                acc[r][e + 4] = fmaf(xv[r].z, g[e].z, acc[r][e + 4]);
                acc[r][e + 4] = fmaf(xv[r].w, g[e].w, acc[r][e + 4]);
            }
#pragma unroll
        for (int r = 0; r < 4; ++r) xv[r] = xn[r];  // dead at it==7
    }

    // ---- fold-reduction: 56 shuffles; lane ends with row (lane&3)'s 8 logits ----
    const int rsel = lane & 1;
    float a2[2][8];
#pragma unroll
    for (int j = 0; j < 2; ++j)
#pragma unroll
        for (int e = 0; e < 8; ++e) {
            const float mine  = rsel ? acc[2 * j + 1][e] : acc[2 * j][e];
            const float other = rsel ? acc[2 * j][e]     : acc[2 * j + 1][e];
            a2[j][e] = mine + __shfl_xor(other, 1);
        }
    const int sel = (lane >> 1) & 1;
    float a1[8];
#pragma unroll
    for (int e = 0; e < 8; ++e) {
        const float mine  = sel ? a2[1][e] : a2[0][e];
        const float other = sel ? a2[0][e] : a2[1][e];
        a1[e] = mine + __shfl_xor(other, 2);
    }
#pragma unroll
    for (int e = 0; e < 8; ++e) {
        float v = a1[e];
        v += __shfl_xor(v, 4);
        v += __shfl_xor(v, 8);
        v += __shfl_xor(v, 16);
        v += __shfl_xor(v, 32);
        a1[e] = v;
    }

    // ---- per-lane top-2 (lowest-index tie-break) ----
    int s0 = 0; float b0 = a1[0];
#pragma unroll
    for (int e = 1; e < 8; ++e)
        if (a1[e] > b0) { b0 = a1[e]; s0 = e; }
    int s1 = 0; float b1 = -3.4e38f;
#pragma unroll
    for (int e = 0; e < 8; ++e) {
        const bool t = (e != s0) && (a1[e] > b1);
        b1 = t ? a1[e] : b1;
        s1 = t ? e : s1;
    }
    const float d  = expf(b1 - b0);          // <= 1
    const float w0 = 1.0f / (1.0f + d);      // p0/(p0+p1)
    const float w1 = d * w0;

    float* out_w = out;                            // [N, 2]
    float* out_m = out + 2 * kN;                   // [E, 2, N]
    float* out_l = out + 2 * kN + 2 * kE * kN;     // [N, 8]

    const int row = lane & 3;
    const int q   = lane >> 2;                     // 0..15

    // mask: lane = em*8 + km*4 + row (bijective over 8x2x4)
    {
        const int em = lane >> 3;
        const int km = (lane >> 2) & 1;
        const int ss = km ? s1 : s0;
        out_m[(long)em * (2 * kN) + (long)km * kN + (n0 + row)] =
            (ss == em) ? 1.0f : 0.0f;
    }
    if (lane < 8)
        out_w[(long)(n0 + row) * 2 + q] = q ? w1 : w0;
    if (lane < 32) {
        float v = a1[0];
#pragma unroll
        for (int e = 1; e < 8; ++e)
            v = (q == e) ? a1[e] : v;
        out_l[(long)(n0 + row) * 8 + q] = v;
    }
}

extern "C" void kernel_launch(void* const* d_in, const int* in_sizes, int n_in,
                              void* d_out, int out_size, void* d_ws, size_t ws_size,
                              hipStream_t stream)
{
    (void)in_sizes; (void)n_in; (void)d_ws; (void)ws_size; (void)out_size;
    const float* x  = (const float*)d_in[0];
    const float* gw = (const float*)d_in[1];
    float* out = (float*)d_out;

    dim3 grid(kN / 32);   // 512 blocks, 32 rows each -> exactly 2 blocks/CU
    dim3 block(512);
    moe_router_kernel<<<grid, block, 0, stream>>>(x, gw, out);
}

// Round 4
// 35.709 us; speedup vs baseline: 1.0944x; 1.0944x over previous
//
#include <hip/hip_runtime.h>
#include <math.h>

// MoE router: x [16384, 2048] f32, gate_w [8, 2048] f32
// outputs (concatenated f32): weights [16384,2] | mask [8,2,16384] | logits [16384,8]

constexpr int kN = 16384;
constexpr int kD = 2048;
constexpr int kE = 8;

using f4 = __attribute__((ext_vector_type(4))) float;

__global__ __launch_bounds__(256, 4)
void moe_router_kernel(const float* __restrict__ x,
                       const float* __restrict__ gw,
                       float* __restrict__ out)
{
    const int lane = threadIdx.x & 63;
    const int wv   = threadIdx.x >> 6;
    const int n0   = blockIdx.x * 16 + wv * 4;   // 4 rows per wave

    const float* xr = x + (long)n0 * kD;

    float acc[4][8];
#pragma unroll
    for (int r = 0; r < 4; ++r)
#pragma unroll
        for (int e = 0; e < 8; ++e) acc[r][e] = 0.f;

    // Column-phase rotation: decorrelate the global column phase across
    // blocks/waves so concurrent reads spread over all HBM channels
    // (lockstep it*1KB phase + 8KB row stride under-uses channels).
    const int off = (blockIdx.x * 5 + wv) & 7;

    // Main sweep: 8 col-iterations, 64 lanes x float4 = 256 cols each.
    // unroll 1: keeps live regs ~90 (< the 128 cap) -> no spills.
#pragma unroll 1
    for (int it = 0; it < 8; ++it) {
        const int c = ((it + off) & 7) * 256 + lane * 4;
        // x first (HBM, longest latency), nontemporal (single-use stream,
        // keep L2 for gate_w).
        f4 xv[4];
#pragma unroll
        for (int r = 0; r < 4; ++r)
            xv[r] = __builtin_nontemporal_load(
                reinterpret_cast<const f4*>(xr + (long)r * kD + c));
        f4 g[8];
#pragma unroll
        for (int e = 0; e < 8; ++e)
            g[e] = *reinterpret_cast<const f4*>(gw + e * kD + c);
#pragma unroll
        for (int r = 0; r < 4; ++r)
#pragma unroll
            for (int e = 0; e < 8; ++e) {
                acc[r][e] = fmaf(xv[r].x, g[e].x, acc[r][e]);
                acc[r][e] = fmaf(xv[r].y, g[e].y, acc[r][e]);
                acc[r][e] = fmaf(xv[r].z, g[e].z, acc[r][e]);
                acc[r][e] = fmaf(xv[r].w, g[e].w, acc[r][e]);
            }
    }

    // ---- Fold-reduction: 56 shuffles. After this, every lane holds all 8
    // logits of row (lane&3), summed over all 64 lanes. ----
    const int rsel = lane & 1;
    float a2[2][8];
#pragma unroll
    for (int j = 0; j < 2; ++j)
#pragma unroll
        for (int e = 0; e < 8; ++e) {
            const float mine  = rsel ? acc[2 * j + 1][e] : acc[2 * j][e];
            const float other = rsel ? acc[2 * j][e]     : acc[2 * j + 1][e];
            a2[j][e] = mine + __shfl_xor(other, 1);
        }
    const int sel = (lane >> 1) & 1;
    float a1[8];
#pragma unroll
    for (int e = 0; e < 8; ++e) {
        const float mine  = sel ? a2[1][e] : a2[0][e];
        const float other = sel ? a2[0][e] : a2[1][e];
        a1[e] = mine + __shfl_xor(other, 2);
    }
#pragma unroll
    for (int e = 0; e < 8; ++e) {
        float v = a1[e];
        v += __shfl_xor(v, 4);
        v += __shfl_xor(v, 8);
        v += __shfl_xor(v, 16);
        v += __shfl_xor(v, 32);
        a1[e] = v;   // logit of (row = lane&3, expert = e)
    }

    // ---- per-lane top-2 (lowest-index tie-break) ----
    int s0 = 0; float b0 = a1[0];
#pragma unroll
    for (int e = 1; e < 8; ++e)
        if (a1[e] > b0) { b0 = a1[e]; s0 = e; }
    int s1 = 0; float b1 = -3.4e38f;
#pragma unroll
    for (int e = 0; e < 8; ++e) {
        const bool t = (e != s0) && (a1[e] > b1);
        b1 = t ? a1[e] : b1;
        s1 = t ? e : s1;
    }
    const float d  = expf(b1 - b0);          // <= 1
    const float w0 = 1.0f / (1.0f + d);      // p0/(p0+p1)
    const float w1 = d * w0;

    float* out_w = out;                            // [N, 2]
    float* out_m = out + 2 * kN;                   // [E, 2, N]
    float* out_l = out + 2 * kN + 2 * kE * kN;     // [N, 8]

    const int row = lane & 3;
    const int q   = lane >> 2;                     // 0..15

    // mask: lane = em*8 + km*4 + row (bijective over 8x2x4)
    {
        const int em = lane >> 3;
        const int km = (lane >> 2) & 1;
        const int ss = km ? s1 : s0;
        out_m[(long)em * (2 * kN) + (long)km * kN + (n0 + row)] =
            (ss == em) ? 1.0f : 0.0f;
    }
    // weights: lanes 0..7 -> (row = lane&3, k = lane>>2)
    if (lane < 8)
        out_w[(long)(n0 + row) * 2 + q] = q ? w1 : w0;
    // logits: lanes 0..31 -> (row = lane&3, e = lane>>2), 128B/row-group
    if (lane < 32) {
        float v = a1[0];
#pragma unroll
        for (int e = 1; e < 8; ++e)
            v = (q == e) ? a1[e] : v;
        out_l[(long)(n0 + row) * 8 + q] = v;
    }
}

extern "C" void kernel_launch(void* const* d_in, const int* in_sizes, int n_in,
                              void* d_out, int out_size, void* d_ws, size_t ws_size,
                              hipStream_t stream)
{
    (void)in_sizes; (void)n_in; (void)d_ws; (void)ws_size; (void)out_size;
    const float* x  = (const float*)d_in[0];
    const float* gw = (const float*)d_in[1];
    float* out = (float*)d_out;

    dim3 grid(kN / 16);   // 1024 blocks, 16 rows each, 4 blocks/CU
    dim3 block(256);
    moe_router_kernel<<<grid, block, 0, stream>>>(x, gw, out);
}